// Round 8
// baseline (3322.469 us; speedup 1.0000x reference)
//
#include <hip/hip_runtime.h>
#include <stdint.h>

#define TT 512
#define BB 256
#define HH 512
#define NOUTC 64
// 16 groups x 16 blocks. R14 = R13 seqlock with latency re-layering:
//  - x_{t+2} HBM loads issued BEFORE the MFMA phase (RT drains under compute,
//    not under the retry check's vmcnt(0) — R13 exposed x RT on the exchange
//    path every step);
//  - stage split into issue (right after publish) / check (after x ds_write
//    and classify filler);
//  - MFMA accumulate chains split 2-way (halved dependent latency).
// Protocol unchanged: flagless seqlock, seq bit in bit0 of low f16 per 8B
// word (|h|<1, <=1 ulp), group-slot stride 2048 ull, bounded retry, ONE
// barrier per step.

typedef _Float16 f16;
typedef f16 f16x8 __attribute__((ext_vector_type(8)));
typedef float f32x4 __attribute__((ext_vector_type(4)));
typedef unsigned long long ull;

__device__ __forceinline__ float sigmoidf_(float x) {
  x = fminf(fmaxf(x, -30.f), 30.f);
  return 1.f / (1.f + __expf(-x));
}
__device__ __forceinline__ float tanhf_(float x) {
  x = fminf(fmaxf(x, -15.f), 15.f);
  float e = __expf(2.f * x);
  return (e - 1.f) / (e + 1.f);
}

__device__ __forceinline__ f16x8 cvt8(const float* __restrict__ src) {
  float4 p0 = *(const float4*)(src);
  float4 p1 = *(const float4*)(src + 4);
  f16x8 a;
  a[0] = (f16)p0.x; a[1] = (f16)p0.y; a[2] = (f16)p0.z; a[3] = (f16)p0.w;
  a[4] = (f16)p1.x; a[5] = (f16)p1.y; a[6] = (f16)p1.z; a[7] = (f16)p1.w;
  return a;
}

__global__ void zero_ws(uint32_t* __restrict__ ws, int nws) {
  int idx = blockIdx.x * blockDim.x + threadIdx.x;
  int stride = gridDim.x * blockDim.x;
  for (int i = idx; i < nws; i += stride) ws[i] = 0u;
}

__global__ __launch_bounds__(256, 1) void lstm_kernel(
    const float* __restrict__ input, const float* __restrict__ dtp,
    const float* __restrict__ W_ih, const float* __restrict__ W_hh,
    const float* __restrict__ b_ih, const float* __restrict__ b_hh,
    const float* __restrict__ W_cls, const float* __restrict__ b_cls,
    float* __restrict__ out, f16* __restrict__ h_buf) {
  __shared__ __align__(16) f16 xh_h[2][16][520];  // h double-buffer (padded)
  __shared__ __align__(16) f16 xb[2][16][136];    // x double-buffer (padded)
  __shared__ __align__(16) f16x8 wlds[16][64];    // W_cls frags (cls blocks)

  const int tid = threadIdx.x;
  const int g = blockIdx.x & 15;   // group: batch slice [g*16, g*16+16)
  const int s = blockIdx.x >> 4;   // sub: hidden slice [s*32, s*32+32)
  const int b0 = g * 16;
  const int w = tid >> 6;          // wave id 0..3
  const int lane = tid & 63;
  const int l = lane & 15;
  const int quad = lane >> 4;
  const int mt_o = s & 3;
  const bool cls_block = (s < 4);
  const int hb = s * 32 + w * 8;   // wave's 8-hidden slice base

  // ---- A-fragments: m-tile0 rows = {i,f}x8h, m-tile1 = {g,o}x8h.
  // D mapping: m=quad*4+r -> gate m>>3, h = hb + (m&7); col n = l.
  f16x8 afrag[2][20];
#pragma unroll
  for (int mp = 0; mp < 2; ++mp) {
    const int grow = (mp * 2 + (l >> 3)) * HH + hb + (l & 7);
#pragma unroll
    for (int it = 0; it < 20; ++it) {
      const int kb = it * 32 + quad * 8;
      const float* src = (kb < 128) ? (W_ih + (size_t)grow * 128 + kb)
                                    : (W_hh + (size_t)grow * HH + (kb - 128));
      afrag[mp][it] = cvt8(src);
    }
  }

  // ---- gate biases (quad<2 lanes): h = hb + (quad&1)*4 + r
  float gb_i[4], gb_f[4], gb_g[4], gb_o[4];
  {
    const int hg = hb + (quad & 1) * 4;
#pragma unroll
    for (int r = 0; r < 4; ++r) {
      gb_i[r] = b_ih[0 * HH + hg + r] + b_hh[0 * HH + hg + r];
      gb_f[r] = b_ih[1 * HH + hg + r] + b_hh[1 * HH + hg + r];
      gb_g[r] = b_ih[2 * HH + hg + r] + b_hh[2 * HH + hg + r];
      gb_o[r] = b_ih[3 * HH + hg + r] + b_hh[3 * HH + hg + r];
    }
  }

  // ---- classifier state (wave0 of s<4 blocks)
  float bcls4[4] = {0.f, 0.f, 0.f, 0.f};
  if (cls_block && w == 0) {
#pragma unroll
    for (int r = 0; r < 4; ++r) bcls4[r] = b_cls[mt_o * 16 + quad * 4 + r];
#pragma unroll
    for (int it = 0; it < 16; ++it)
      wlds[it][lane] =
          cvt8(W_cls + (size_t)(mt_o * 16 + l) * HH + it * 32 + quad * 8);
  }

  auto classify = [&](int slot, int tt) {
    f32x4 oa = {0.f, 0.f, 0.f, 0.f}, ob = {0.f, 0.f, 0.f, 0.f};
#pragma unroll
    for (int it = 0; it < 16; it += 2) {
      f16x8 ba = *(const f16x8*)(&xh_h[slot][l][it * 32 + quad * 8]);
      f16x8 bb = *(const f16x8*)(&xh_h[slot][l][(it + 1) * 32 + quad * 8]);
      oa = __builtin_amdgcn_mfma_f32_16x16x32_f16(wlds[it][lane], ba, oa, 0, 0, 0);
      ob = __builtin_amdgcn_mfma_f32_16x16x32_f16(wlds[it + 1][lane], bb, ob, 0, 0, 0);
    }
    float4 o;
    o.x = oa[0] + ob[0] + bcls4[0];
    o.y = oa[1] + ob[1] + bcls4[1];
    o.z = oa[2] + ob[2] + bcls4[2];
    o.w = oa[3] + ob[3] + bcls4[3];
    *(float4*)(out + ((size_t)tt * BB + b0 + l) * NOUTC + mt_o * 16 +
               quad * 4) = o;
  };

  // ---- prologue: zero xh_h[0] (h_{-1}=0), x_0 -> xb[0], issue x_1 loads
  {
    ull* zp = (ull*)&xh_h[0][0][0];  // 16*520 f16 = 2080 ull
    for (int i = tid; i < 2080; i += 256) zp[i] = 0ull;
  }
  const int kx = tid & 127;
  const int nx0 = tid >> 7;
#pragma unroll
  for (int ii = 0; ii < 8; ++ii) {
    const int row = b0 + ii * 2 + nx0;
    float v = (kx < 127) ? input[(size_t)row * 127 + kx] : dtp[row];
    xb[0][ii * 2 + nx0][kx] = (f16)v;
  }
  float xf[8];   // x_{t+1} (loaded one iter ahead)
#pragma unroll
  for (int ii = 0; ii < 8; ++ii) {
    const int row = BB + b0 + ii * 2 + nx0;  // t=1
    xf[ii] = (kx < 127) ? input[(size_t)row * 127 + kx] : dtp[row];
  }
  float cc[4] = {0.f, 0.f, 0.f, 0.f};
  __syncthreads();

  for (int t = 0; t < TT; ++t) {
    const int xs = t & 1;

    // ---- issue x_{t+2} loads FIRST: RT drains under the MFMA phase
    float xf2[8];
    if (t + 2 < TT) {
#pragma unroll
      for (int ii = 0; ii < 8; ++ii) {
        const int row = (t + 2) * BB + b0 + ii * 2 + nx0;
        xf2[ii] = (kx < 127) ? input[(size_t)row * 127 + kx] : dtp[row];
      }
    }

    // ---- gates: [4 gates x 8 hid] x [16 batch], K=640; 2-way split chains
    f32x4 a0a = {0.f, 0.f, 0.f, 0.f}, a0b = {0.f, 0.f, 0.f, 0.f};
    f32x4 a1a = {0.f, 0.f, 0.f, 0.f}, a1b = {0.f, 0.f, 0.f, 0.f};
#pragma unroll
    for (int it = 0; it < 4; it += 2) {
      f16x8 b0f = *(const f16x8*)(&xb[xs][l][it * 32 + quad * 8]);
      f16x8 b1f = *(const f16x8*)(&xb[xs][l][(it + 1) * 32 + quad * 8]);
      a0a = __builtin_amdgcn_mfma_f32_16x16x32_f16(afrag[0][it], b0f, a0a, 0, 0, 0);
      a1a = __builtin_amdgcn_mfma_f32_16x16x32_f16(afrag[1][it], b0f, a1a, 0, 0, 0);
      a0b = __builtin_amdgcn_mfma_f32_16x16x32_f16(afrag[0][it + 1], b1f, a0b, 0, 0, 0);
      a1b = __builtin_amdgcn_mfma_f32_16x16x32_f16(afrag[1][it + 1], b1f, a1b, 0, 0, 0);
    }
#pragma unroll
    for (int kk = 0; kk < 16; kk += 2) {
      f16x8 b0f = *(const f16x8*)(&xh_h[xs][l][kk * 32 + quad * 8]);
      f16x8 b1f = *(const f16x8*)(&xh_h[xs][l][(kk + 1) * 32 + quad * 8]);
      a0a = __builtin_amdgcn_mfma_f32_16x16x32_f16(afrag[0][4 + kk], b0f, a0a, 0, 0, 0);
      a1a = __builtin_amdgcn_mfma_f32_16x16x32_f16(afrag[1][4 + kk], b0f, a1a, 0, 0, 0);
      a0b = __builtin_amdgcn_mfma_f32_16x16x32_f16(afrag[0][5 + kk], b1f, a0b, 0, 0, 0);
      a1b = __builtin_amdgcn_mfma_f32_16x16x32_f16(afrag[1][5 + kk], b1f, a1b, 0, 0, 0);
    }
    f32x4 acc0 = a0a + a0b, acc1 = a1a + a1b;

    // ---- cell update in regs; f,o come from lane^32
    float fsh[4], osh[4];
#pragma unroll
    for (int r = 0; r < 4; ++r) {
      fsh[r] = __shfl_xor(acc0[r], 32, 64);
      osh[r] = __shfl_xor(acc1[r], 32, 64);
    }
    if (quad < 2) {
      union { f16 h4[4]; ull u; } pk;
#pragma unroll
      for (int r = 0; r < 4; ++r) {
        float vi = acc0[r] + gb_i[r];
        float vf = fsh[r] + gb_f[r];
        float vg = acc1[r] + gb_g[r];
        float vo = osh[r] + gb_o[r];
        float iv = sigmoidf_(vi), fv = sigmoidf_(vf);
        float gv = tanhf_(vg), ov = sigmoidf_(vo);
        cc[r] = fv * cc[r] + iv * gv;
        pk.h4[r] = (f16)(ov * tanhf_(cc[r]));
      }
      // force seq bit into bit0 of the low f16 (<=1 ulp, |h|<1)
      pk.u = (pk.u & ~1ull) | (ull)((((t >> 1) & 1) ^ 1));
      __hip_atomic_store(
          (ull*)(h_buf + ((size_t)(t & 1) * 16 + g) * (16 * HH) +
                 (size_t)l * HH + hb + quad * 4),
          pk.u, __ATOMIC_RELAXED, __HIP_MEMORY_SCOPE_AGENT);
    }
    asm volatile("" ::: "memory");  // publish stays above the stage/retry

    // ---- stage h_t: ISSUE loads now (head start before the check)
    const ull* hbp = (const ull*)h_buf + ((size_t)(t & 1) * 16 + g) * 2048;
    ull v[8];
#pragma unroll
    for (int ci = 0; ci < 8; ++ci)
      v[ci] = __hip_atomic_load(hbp + ci * 256 + tid, __ATOMIC_RELAXED,
                                __HIP_MEMORY_SCOPE_AGENT);

    // ---- filler under the load RT: x_{t+1} -> xb[(t+1)&1], classify
    if (t + 1 < TT) {
#pragma unroll
      for (int ii = 0; ii < 8; ++ii)
        xb[xs ^ 1][ii * 2 + nx0][kx] = (f16)xf[ii];
    }
    if (t > 0 && cls_block && w == 0) classify(xs, t - 1);

    // ---- CHECK seq bits (bounded retry; reload only stale words)
    {
      const uint32_t e = (uint32_t)((((t >> 1) & 1) ^ 1));
      for (int spin = 0; spin < (1 << 16); ++spin) {
        uint32_t stale = 0;
#pragma unroll
        for (int ci = 0; ci < 8; ++ci)
          if (((uint32_t)v[ci] ^ e) & 1u) stale |= 1u << ci;
        if (!stale) break;
        __builtin_amdgcn_s_sleep(1);
#pragma unroll
        for (int ci = 0; ci < 8; ++ci)
          if (stale & (1u << ci))
            v[ci] = __hip_atomic_load(hbp + ci * 256 + tid, __ATOMIC_RELAXED,
                                      __HIP_MEMORY_SCOPE_AGENT);
      }
#pragma unroll
      for (int ci = 0; ci < 8; ++ci) {
        const int c2 = ci * 256 + tid;
        *(ull*)(&xh_h[xs ^ 1][c2 >> 7][(c2 & 127) * 4]) = v[ci];
      }
    }

    // ---- rotate x pipeline regs
    if (t + 2 < TT) {
#pragma unroll
      for (int ii = 0; ii < 8; ++ii) xf[ii] = xf2[ii];
    }

    __syncthreads();  // the ONE barrier: h/x writes -> next-iter reads
  }

  // ---- tail: out[TT-1] from h_{TT-1} (staged into xh_h[TT&1]==[0])
  if (cls_block && w == 0) classify(0, TT - 1);
}

extern "C" void kernel_launch(void* const* d_in, const int* in_sizes, int n_in,
                              void* d_out, int out_size, void* d_ws,
                              size_t ws_size, hipStream_t stream) {
  const float* input = (const float*)d_in[0];
  const float* dtp = (const float*)d_in[1];
  const float* W_ih = (const float*)d_in[2];
  const float* W_hh = (const float*)d_in[3];
  const float* b_ih = (const float*)d_in[4];
  const float* b_hh = (const float*)d_in[5];
  const float* W_cls = (const float*)d_in[6];
  const float* b_cls = (const float*)d_in[7];
  float* out = (float*)d_out;

  // ws layout: [0, 512K): h double-buffer [2][16][16][512] f16.
  // Must be zeroed: seq bit0==0 reads as stale (expected bit is 1 for t=0,1).
  f16* h_buf = (f16*)d_ws;
  const int nws_words = (2 * 16 * 16 * HH * 2) / 4;  // 131072

  zero_ws<<<256, 256, 0, stream>>>((uint32_t*)d_ws, nws_words);
  lstm_kernel<<<256, 256, 0, stream>>>(input, dtp, W_ih, W_hh, b_ih, b_hh,
                                       W_cls, b_cls, out, h_buf);
}